// Round 10
// baseline (553.032 us; speedup 1.0000x reference)
//
#include <hip/hip_runtime.h>

#define N_NODES 50000
#define N_REL 16
#define D 128
#define N_SEG (N_NODES * N_REL)  // 800000
#define N_SEG4 (N_SEG / 4)       // 200000 int4 tiles of cnt

typedef short bf16x8 __attribute__((ext_vector_type(8)));
typedef float f32x4 __attribute__((ext_vector_type(4)));
typedef unsigned short u16;
typedef unsigned int u32;

__device__ __forceinline__ u16 f32_to_bf16(float f) {
  u32 u = __builtin_bit_cast(u32, f);
  u32 r = (u + 0x7FFFu + ((u >> 16) & 1u)) >> 16;
  return (u16)r;
}

// ---------------- per-(dst,rel) edge counts (2 edges/thread) ----------------
__global__ __launch_bounds__(256) void k_count(const int* __restrict__ dst,
                                               const int* __restrict__ rel,
                                               int* __restrict__ cnt, int E) {
  int e = (blockIdx.x * blockDim.x + threadIdx.x) * 2;
  if (e < E)     atomicAdd(&cnt[dst[e] * N_REL + rel[e]], 1);
  if (e + 1 < E) atomicAdd(&cnt[dst[e + 1] * N_REL + rel[e + 1]], 1);
}

// ---------------- scan stage 1: 1024-int tiles (int4), per-block sums ----------
__global__ __launch_bounds__(256) void k_bsum2(const int4* __restrict__ cnt4,
                                               int* __restrict__ bsum, int n4) {
  __shared__ int sm[256];
  int idx = blockIdx.x * 256 + threadIdx.x;
  int v = 0;
  if (idx < n4) { int4 c = cnt4[idx]; v = c.x + c.y + c.z + c.w; }
  sm[threadIdx.x] = v;
  __syncthreads();
  for (int s = 128; s > 0; s >>= 1) {
    if (threadIdx.x < s) sm[threadIdx.x] += sm[threadIdx.x + s];
    __syncthreads();
  }
  if (threadIdx.x == 0) bsum[blockIdx.x] = sm[0];
}

// ---------------- scan stage 2: single-iteration exclusive scan (nb <= 1024) ----
__global__ __launch_bounds__(1024) void k_bscan2(int* __restrict__ bsum, int nb) {
  __shared__ int sm[1024];
  int i = threadIdx.x;
  int v = (i < nb) ? bsum[i] : 0;
  sm[i] = v;
  __syncthreads();
  for (int s = 1; s < 1024; s <<= 1) {
    int t = (i >= s) ? sm[i - s] : 0;
    __syncthreads();
    sm[i] += t;
    __syncthreads();
  }
  if (i < nb) bsum[i] = sm[i] - v;   // exclusive
}

// ---------------- scan stage 3: int4 per-element exclusive offsets ----------------
__global__ __launch_bounds__(256) void k_off2(const int4* __restrict__ cnt4,
                                              const int* __restrict__ bsum,
                                              int* __restrict__ off, int n4) {
  __shared__ int sm[256];
  int idx = blockIdx.x * 256 + threadIdx.x;
  int4 c = {0, 0, 0, 0};
  if (idx < n4) c = cnt4[idx];
  int tsum = c.x + c.y + c.z + c.w;
  sm[threadIdx.x] = tsum;
  __syncthreads();
  for (int s = 1; s < 256; s <<= 1) {
    int t = (threadIdx.x >= s) ? sm[threadIdx.x - s] : 0;
    __syncthreads();
    sm[threadIdx.x] += t;
    __syncthreads();
  }
  int base = bsum[blockIdx.x] + sm[threadIdx.x] - tsum;
  if (idx < n4) {
    int4 o;
    o.x = base;
    o.y = base + c.x;
    o.z = o.y + c.y;
    o.w = o.z + c.z;
    ((int4*)off)[idx] = o;
    if (idx == n4 - 1) off[4 * n4] = o.w + c.w;  // off[N_SEG] = E
  }
}

// ---------------- CSR fill (countdown; 2 edges/thread) ----------------
__global__ __launch_bounds__(256) void k_fill(const int* __restrict__ src,
                                              const int* __restrict__ dst,
                                              const int* __restrict__ rel,
                                              const int* __restrict__ off,
                                              int* __restrict__ cnt,
                                              int* __restrict__ bucket, int E) {
  int e = (blockIdx.x * blockDim.x + threadIdx.x) * 2;
  if (e < E) {
    int seg = dst[e] * N_REL + rel[e];
    int old = atomicSub(&cnt[seg], 1);          // old in [1, cnt]
    bucket[off[seg] + old - 1] = src[e];
  }
  if (e + 1 < E) {
    int seg = dst[e + 1] * N_REL + rel[e + 1];
    int old = atomicSub(&cnt[seg], 1);
    bucket[off[seg] + old - 1] = src[e + 1];
  }
}

// ---------------- fused prep: cnt-zero + bucket-pad + f32->bf16 + weight frags ----
__device__ __forceinline__ void wfrag_one(const float* __restrict__ W,
                                          u16* __restrict__ Wf, int tid) {
  int lane = tid & 63;
  int t = (tid >> 6) & 7;
  int kb = tid >> 9;
  int h = t * 16 + (lane & 15);
  int kbase = kb * 32 + ((lane >> 4) << 3);
  bf16x8 frag;
#pragma unroll
  for (int j = 0; j < 8; ++j) {
    int k = kbase + j;
    frag[j] = (short)f32_to_bf16(W[(size_t)(k >> 7) * (D * D) + (size_t)(k & 127) * D + h]);
  }
  *(bf16x8*)(Wf + (size_t)tid * 8) = frag;
}

#define ZERO_U4 N_SEG4                   // 200,000 uint4 of cnt
#define CVT_N4 (N_NODES * D / 4)         // 1,600,000
#define WF_T (64 * 8 * 64)               // 32768
#define RF_T (4 * 8 * 64)                // 2048
#define PREP_TOTAL (ZERO_U4 + CVT_N4 + 2 * WF_T + 2 * RF_T)

__global__ __launch_bounds__(256) void k_prep(int* __restrict__ cnt,
                                              int* __restrict__ bucket, int E,
                                              const float* __restrict__ emb,
                                              u16* __restrict__ embb,
                                              const float* __restrict__ W1,
                                              u16* __restrict__ Wf1,
                                              const float* __restrict__ W2,
                                              u16* __restrict__ Wf2,
                                              const float* __restrict__ R1,
                                              u16* __restrict__ Rf1,
                                              const float* __restrict__ R2,
                                              u16* __restrict__ Rf2) {
  int tid = blockIdx.x * blockDim.x + threadIdx.x;
  if (tid < 32) bucket[E + tid] = 0;   // pad for phase-1 prefetch over-read
  if (tid < ZERO_U4) {
    uint4 z; z.x = z.y = z.z = z.w = 0u;
    ((uint4*)cnt)[tid] = z;
    return;
  }
  int u = tid - ZERO_U4;
  if (u < CVT_N4) {
    float4 v = ((const float4*)emb)[u];
    u32 p0 = (u32)f32_to_bf16(v.x) | ((u32)f32_to_bf16(v.y) << 16);
    u32 p1 = (u32)f32_to_bf16(v.z) | ((u32)f32_to_bf16(v.w) << 16);
    ((u32*)embb)[u * 2] = p0;
    ((u32*)embb)[u * 2 + 1] = p1;
    return;
  }
  u -= CVT_N4;
  if (u < WF_T) { wfrag_one(W1, Wf1, u); return; }
  u -= WF_T;
  if (u < WF_T) { wfrag_one(W2, Wf2, u); return; }
  u -= WF_T;
  if (u < RF_T) { wfrag_one(R1, Rf1, u); return; }
  u -= RF_T;
  if (u < RF_T) { wfrag_one(R2, Rf2, u); return; }
}

// ---------------- fused RGCN layer v3: pipelined streaming gather + MFMA ----------
// 512 threads (8 waves), one 16-node tile per block.
// Phase 1 (the R10 rebuild of R2's coalesced gather): wave w owns nodes
//   {2w, 2w+1} -> its 32 (node,rel) segments form a CONTIGUOUS bucket window.
//   The wave streams the window flat with an 8-deep rotating row pipeline
//   (1 coalesced 256B row-load per edge = 4 TA segments vs v1's 64; exact trip
//   count, not max-over-16-lanes). Segment boundaries flushed from staged offs
//   (uniform scalar control). Mean rows written bf16 to LDS agg with the
//   R2-verified chunk^m swizzle.
// Phase 2 (verbatim from the correctness-verified R2 kernel): wave w owns
//   output column tile t=w across all 16 rels + root; A-frags via swizzled
//   ds_read_b128; B-frags streamed from L2-resident Wf; acc = 1 f32x4;
//   direct store, no cross-wave reduce.
template <int L>  // L=1: bf16 out + ReLU; L=2: f32 out
__global__ __launch_bounds__(512) void k_layer(const int* __restrict__ off,
                                               const int* __restrict__ bucket,
                                               const u16* __restrict__ x,    // [N,128] bf16
                                               const u16* __restrict__ Wf,   // 64 kb frag-linear
                                               const u16* __restrict__ Rf,   // 4 kb frag-linear
                                               const float* __restrict__ bias,
                                               u16* __restrict__ outb,
                                               float* __restrict__ outf) {
  __shared__ __align__(16) u32 agg[16 * 16 * 64];  // 64 KB: [seg=m*16+r][64 u32]
  __shared__ int offs_sm[257];
  int tid = threadIdx.x;
  int w = tid >> 6;                 // wave 0..7
  int lane = tid & 63;
  int node0 = blockIdx.x << 4;      // 50000 = 3125*16, exact grid

  if (tid < 257) offs_sm[tid] = off[(node0 << 4) + tid];
  __syncthreads();

  const u32* xw = (const u32*)x;    // bf16x2 words

  // ================= phase 1: streaming gather-mean =================
  int sbase = w << 5;               // first seg (node 2w, rel 0)
  int W0 = __builtin_amdgcn_readfirstlane(offs_sm[sbase]);
  int W1 = __builtin_amdgcn_readfirstlane(offs_sm[sbase + 32]);
  int s = 0;
  int segstart = W0;
  int onext = __builtin_amdgcn_readfirstlane(offs_sm[sbase + 1]);
  float aL = 0.0f, aH = 0.0f;

  auto flushAt = [&](int pos) {
    while (s < 32 && pos == onext) {
      int len = onext - segstart;
      float sc = (len > 0) ? 1.0f / (float)len : 0.0f;
      u32 p = (u32)f32_to_bf16(aL * sc) | ((u32)f32_to_bf16(aH * sc) << 16);
      int seg = sbase + s;
      int mrow = seg >> 4;
      agg[(seg << 6) + ((((lane >> 2) ^ mrow) << 2) | (lane & 3))] = p;
      aL = 0.0f; aH = 0.0f;
      segstart = onext;
      ++s;
      onext = (s < 32) ? __builtin_amdgcn_readfirstlane(offs_sm[sbase + s + 1])
                       : 0x7FFFFFFF;
    }
  };
  flushAt(W0);                      // leading empty segments

  u32 rbuf[8];
  int ibuf[8];
#pragma unroll
  for (int k = 0; k < 8; ++k) {     // prologue: rows W0..W0+7 + ids W0+8..W0+15
    int idx = __builtin_amdgcn_readfirstlane(bucket[W0 + k]);
    rbuf[k] = xw[((size_t)(u32)idx << 6) + lane];
    ibuf[k] = __builtin_amdgcn_readfirstlane(bucket[W0 + 8 + k]);
  }

  int i = W0;
  while (i + 16 <= W1) {            // main: 8 rows/chunk, loads 8 ahead, ids 16 ahead
#pragma unroll
    for (int k = 0; k < 8; ++k) {
      u32 u = rbuf[k];
      aL += __builtin_bit_cast(float, u << 16);
      aH += __builtin_bit_cast(float, u & 0xFFFF0000u);
      flushAt(i + k + 1);
      rbuf[k] = xw[((size_t)(u32)ibuf[k] << 6) + lane];
      ibuf[k] = __builtin_amdgcn_readfirstlane(bucket[i + k + 16]);
    }
    i += 8;
  }

  int n = W1 - i;                   // tail: 0..15 rows
#pragma unroll
  for (int k = 0; k < 8; ++k) {
    if (k < n) {
      u32 u = rbuf[k];
      aL += __builtin_bit_cast(float, u << 16);
      aH += __builtin_bit_cast(float, u & 0xFFFF0000u);
      flushAt(i + k + 1);
    }
  }
  u32 r2[8];
#pragma unroll
  for (int k = 0; k < 8; ++k)
    if (8 + k < n) r2[k] = xw[((size_t)(u32)ibuf[k] << 6) + lane];
#pragma unroll
  for (int k = 0; k < 8; ++k) {
    if (8 + k < n) {
      u32 u = r2[k];
      aL += __builtin_bit_cast(float, u << 16);
      aH += __builtin_bit_cast(float, u & 0xFFFF0000u);
      flushAt(i + 8 + k + 1);
    }
  }
  __syncthreads();

  // ================= phase 2: MFMA; wave w owns column tile t=w =================
  int q = lane >> 4;
  int m = lane & 15;
  const u16* aggh = (const u16*)agg;

  f32x4 acc;
#pragma unroll
  for (int j = 0; j < 4; ++j) acc[j] = 0.0f;

  // root term
  {
    const u16* xr = x + ((size_t)(node0 + m) << 7) + (q << 3);
#pragma unroll
    for (int kb = 0; kb < 4; ++kb) {
      bf16x8 a = *(const bf16x8*)(xr + kb * 32);
      bf16x8 b = *(const bf16x8*)(Rf + ((((kb << 3) + w) << 9) | (lane << 3)));
      acc = __builtin_amdgcn_mfma_f32_16x16x32_bf16(a, b, acc, 0, 0, 0);
    }
  }

  // 16 relations
  for (int r = 0; r < 16; ++r) {
#pragma unroll
    for (int kb = 0; kb < 4; ++kb) {
      int c = ((kb << 2) | q) ^ m;  // swizzled chunk
      bf16x8 a = *(const bf16x8*)(aggh + ((((m << 4) | r) << 7) | (c << 3)));
      bf16x8 b = *(const bf16x8*)(Wf + (((((r << 2) | kb) << 3) + w) << 9) + (lane << 3));
      acc = __builtin_amdgcn_mfma_f32_16x16x32_bf16(a, b, acc, 0, 0, 0);
    }
  }

  // epilogue: C layout col=m, row=q*4+j [m89]; t = w
  int h = (w << 4) + m;
  float bv = bias[h];
#pragma unroll
  for (int j = 0; j < 4; ++j) {
    int n2 = node0 + (q << 2) + j;
    float v = acc[j] + bv;
    if (L == 1) {
      v = v > 0.0f ? v : 0.0f;
      outb[(size_t)n2 * D + h] = f32_to_bf16(v);
    } else {
      outf[(size_t)n2 * D + h] = v;
    }
  }
}

extern "C" void kernel_launch(void* const* d_in, const int* in_sizes, int n_in,
                              void* d_out, int out_size, void* d_ws, size_t ws_size,
                              hipStream_t stream) {
  const int* edge_index = (const int*)d_in[0];
  const int* edge_type  = (const int*)d_in[1];
  const float* emb   = (const float*)d_in[2];
  const float* W1    = (const float*)d_in[3];
  const float* root1 = (const float*)d_in[4];
  const float* b1    = (const float*)d_in[5];
  const float* W2    = (const float*)d_in[6];
  const float* root2 = (const float*)d_in[7];
  const float* b2    = (const float*)d_in[8];
  float* out = (float*)d_out;

  int E = in_sizes[0] / 2;
  const int* src = edge_index;      // row 0
  const int* dst = edge_index + E;  // row 1
  int scanBlocks = (N_SEG4 + 255) / 256;  // 782 (1024-int tiles)

  char* ws = (char*)d_ws;
  size_t off_b = 0;
  auto take = [&](size_t bytes) -> char* {
    char* p = ws + off_b;
    off_b += (bytes + 255) & ~(size_t)255;
    return p;
  };
  int*   cnt    = (int*)take((size_t)N_SEG * 4);
  int*   offs   = (int*)take((size_t)(N_SEG + 1) * 4);
  int*   bsum   = (int*)take((size_t)scanBlocks * 4);
  int*   bucket = (int*)take((size_t)(E + 32) * 4);  // +32 pad (zeroed in k_prep)
  u16*   embb   = (u16*)take((size_t)N_NODES * D * 2);
  u16*   x1     = (u16*)take((size_t)N_NODES * D * 2);
  u16*   Wf1    = (u16*)take((size_t)64 * 8 * 512 * 2);
  u16*   Rf1    = (u16*)take((size_t)4 * 8 * 512 * 2);
  u16*   Wf2    = (u16*)take((size_t)64 * 8 * 512 * 2);
  u16*   Rf2    = (u16*)take((size_t)4 * 8 * 512 * 2);
  // total ~41 MB — fits comfortably

  int eBlocks2 = ((E + 1) / 2 + 255) / 256;  // 2 edges/thread
  int layerBlocks = N_NODES / 16;            // 3125 blocks

  // --- fused prep (zeroes cnt + pads bucket + converts emb + weight frags) ---
  k_prep<<<(PREP_TOTAL + 255) / 256, 256, 0, stream>>>(cnt, bucket, E, emb, embb,
                                                       W1, Wf1, W2, Wf2,
                                                       root1, Rf1, root2, Rf2);

  // --- CSR build (shared by both layers) ---
  k_count<<<eBlocks2, 256, 0, stream>>>(dst, edge_type, cnt, E);
  k_bsum2<<<scanBlocks, 256, 0, stream>>>((const int4*)cnt, bsum, N_SEG4);
  k_bscan2<<<1, 1024, 0, stream>>>(bsum, scanBlocks);
  k_off2<<<scanBlocks, 256, 0, stream>>>((const int4*)cnt, bsum, offs, N_SEG4);
  k_fill<<<eBlocks2, 256, 0, stream>>>(src, dst, edge_type, offs, cnt, bucket, E);

  // --- two fused layers ---
  k_layer<1><<<layerBlocks, 512, 0, stream>>>(offs, bucket, embb, Wf1, Rf1, b1,
                                              x1, nullptr);
  k_layer<2><<<layerBlocks, 512, 0, stream>>>(offs, bucket, x1, Wf2, Rf2, b2,
                                              nullptr, out);
}

// Round 11
// 512.090 us; speedup vs baseline: 1.0799x; 1.0799x over previous
//
#include <hip/hip_runtime.h>

#define N_NODES 50000
#define N_REL 16
#define D 128
#define N_SEG (N_NODES * N_REL)  // 800000
#define N_SEG4 (N_SEG / 4)       // 200000 int4 tiles of cnt

typedef short bf16x8 __attribute__((ext_vector_type(8)));
typedef float f32x4 __attribute__((ext_vector_type(4)));
typedef unsigned short u16;
typedef unsigned int u32;

__device__ __forceinline__ u16 f32_to_bf16(float f) {
  u32 u = __builtin_bit_cast(u32, f);
  u32 r = (u + 0x7FFFu + ((u >> 16) & 1u)) >> 16;
  return (u16)r;
}
__device__ __forceinline__ float bf16_to_f32(u16 h) {
  u32 u = ((u32)h) << 16;
  return __builtin_bit_cast(float, u);
}

// ---------------- per-(dst,rel) edge counts (4 edges/thread, int4 loads) ---------
__global__ __launch_bounds__(256) void k_count(const int* __restrict__ dst,
                                               const int* __restrict__ rel,
                                               int* __restrict__ cnt, int E) {
  int e = (blockIdx.x * blockDim.x + threadIdx.x) * 4;
  if (e + 3 < E) {
    int4 d = *(const int4*)(dst + e);
    int4 r = *(const int4*)(rel + e);
    atomicAdd(&cnt[d.x * N_REL + r.x], 1);
    atomicAdd(&cnt[d.y * N_REL + r.y], 1);
    atomicAdd(&cnt[d.z * N_REL + r.z], 1);
    atomicAdd(&cnt[d.w * N_REL + r.w], 1);
  } else {
    for (; e < E; ++e) atomicAdd(&cnt[dst[e] * N_REL + rel[e]], 1);
  }
}

// ---------------- scan stage 1: 1024-int tiles (int4), per-block sums ----------
__global__ __launch_bounds__(256) void k_bsum2(const int4* __restrict__ cnt4,
                                               int* __restrict__ bsum, int n4) {
  __shared__ int sm[256];
  int idx = blockIdx.x * 256 + threadIdx.x;
  int v = 0;
  if (idx < n4) { int4 c = cnt4[idx]; v = c.x + c.y + c.z + c.w; }
  sm[threadIdx.x] = v;
  __syncthreads();
  for (int s = 128; s > 0; s >>= 1) {
    if (threadIdx.x < s) sm[threadIdx.x] += sm[threadIdx.x + s];
    __syncthreads();
  }
  if (threadIdx.x == 0) bsum[blockIdx.x] = sm[0];
}

// ---------------- scan stage 2: single-iteration exclusive scan (nb <= 1024) ----
__global__ __launch_bounds__(1024) void k_bscan2(int* __restrict__ bsum, int nb) {
  __shared__ int sm[1024];
  int i = threadIdx.x;
  int v = (i < nb) ? bsum[i] : 0;
  sm[i] = v;
  __syncthreads();
  for (int s = 1; s < 1024; s <<= 1) {
    int t = (i >= s) ? sm[i - s] : 0;
    __syncthreads();
    sm[i] += t;
    __syncthreads();
  }
  if (i < nb) bsum[i] = sm[i] - v;   // exclusive
}

// ---------------- scan stage 3: int4 per-element exclusive offsets ----------------
__global__ __launch_bounds__(256) void k_off2(const int4* __restrict__ cnt4,
                                              const int* __restrict__ bsum,
                                              int* __restrict__ off, int n4) {
  __shared__ int sm[256];
  int idx = blockIdx.x * 256 + threadIdx.x;
  int4 c = {0, 0, 0, 0};
  if (idx < n4) c = cnt4[idx];
  int tsum = c.x + c.y + c.z + c.w;
  sm[threadIdx.x] = tsum;
  __syncthreads();
  for (int s = 1; s < 256; s <<= 1) {
    int t = (threadIdx.x >= s) ? sm[threadIdx.x - s] : 0;
    __syncthreads();
    sm[threadIdx.x] += t;
    __syncthreads();
  }
  int base = bsum[blockIdx.x] + sm[threadIdx.x] - tsum;
  if (idx < n4) {
    int4 o;
    o.x = base;
    o.y = base + c.x;
    o.z = o.y + c.y;
    o.w = o.z + c.z;
    ((int4*)off)[idx] = o;
    if (idx == n4 - 1) off[4 * n4] = o.w + c.w;  // off[N_SEG] = E
  }
}

// ---------------- CSR fill (countdown; 4 edges/thread, int4 loads) ----------------
__global__ __launch_bounds__(256) void k_fill(const int* __restrict__ src,
                                              const int* __restrict__ dst,
                                              const int* __restrict__ rel,
                                              const int* __restrict__ off,
                                              int* __restrict__ cnt,
                                              int* __restrict__ bucket, int E) {
  int e = (blockIdx.x * blockDim.x + threadIdx.x) * 4;
  if (e + 3 < E) {
    int4 sv = *(const int4*)(src + e);
    int4 d  = *(const int4*)(dst + e);
    int4 r  = *(const int4*)(rel + e);
    int seg, old;
    seg = d.x * N_REL + r.x; old = atomicSub(&cnt[seg], 1);
    bucket[off[seg] + old - 1] = sv.x;
    seg = d.y * N_REL + r.y; old = atomicSub(&cnt[seg], 1);
    bucket[off[seg] + old - 1] = sv.y;
    seg = d.z * N_REL + r.z; old = atomicSub(&cnt[seg], 1);
    bucket[off[seg] + old - 1] = sv.z;
    seg = d.w * N_REL + r.w; old = atomicSub(&cnt[seg], 1);
    bucket[off[seg] + old - 1] = sv.w;
  } else {
    for (; e < E; ++e) {
      int seg = dst[e] * N_REL + rel[e];
      int old = atomicSub(&cnt[seg], 1);          // old in [1, cnt]
      bucket[off[seg] + old - 1] = src[e];
    }
  }
}

// ---------------- fused prep: cnt-zero + f32->bf16 convert + 4 weight-frag builds --
__device__ __forceinline__ void wfrag_one(const float* __restrict__ W,
                                          u16* __restrict__ Wf, int tid) {
  int lane = tid & 63;
  int t = (tid >> 6) & 7;
  int kb = tid >> 9;
  int h = t * 16 + (lane & 15);
  int kbase = kb * 32 + ((lane >> 4) << 3);
  bf16x8 frag;
#pragma unroll
  for (int j = 0; j < 8; ++j) {
    int k = kbase + j;
    frag[j] = (short)f32_to_bf16(W[(size_t)(k >> 7) * (D * D) + (size_t)(k & 127) * D + h]);
  }
  *(bf16x8*)(Wf + (size_t)tid * 8) = frag;
}

#define ZERO_U4 N_SEG4                   // 200,000 uint4 of cnt
#define CVT_N4 (N_NODES * D / 4)         // 1,600,000
#define WF_T (64 * 8 * 64)               // 32768
#define RF_T (4 * 8 * 64)                // 2048
#define PREP_TOTAL (ZERO_U4 + CVT_N4 + 2 * WF_T + 2 * RF_T)

__global__ __launch_bounds__(256) void k_prep(int* __restrict__ cnt,
                                              const float* __restrict__ emb,
                                              u16* __restrict__ embb,
                                              const float* __restrict__ W1,
                                              u16* __restrict__ Wf1,
                                              const float* __restrict__ W2,
                                              u16* __restrict__ Wf2,
                                              const float* __restrict__ R1,
                                              u16* __restrict__ Rf1,
                                              const float* __restrict__ R2,
                                              u16* __restrict__ Rf2) {
  int tid = blockIdx.x * blockDim.x + threadIdx.x;
  if (tid < ZERO_U4) {
    uint4 z; z.x = z.y = z.z = z.w = 0u;
    ((uint4*)cnt)[tid] = z;
    return;
  }
  int u = tid - ZERO_U4;
  if (u < CVT_N4) {
    float4 v = ((const float4*)emb)[u];
    u32 p0 = (u32)f32_to_bf16(v.x) | ((u32)f32_to_bf16(v.y) << 16);
    u32 p1 = (u32)f32_to_bf16(v.z) | ((u32)f32_to_bf16(v.w) << 16);
    ((u32*)embb)[u * 2] = p0;
    ((u32*)embb)[u * 2 + 1] = p1;
    return;
  }
  u -= CVT_N4;
  if (u < WF_T) { wfrag_one(W1, Wf1, u); return; }
  u -= WF_T;
  if (u < WF_T) { wfrag_one(W2, Wf2, u); return; }
  u -= WF_T;
  if (u < RF_T) { wfrag_one(R1, Rf1, u); return; }
  u -= RF_T;
  if (u < RF_T) { wfrag_one(R2, Rf2, u); return; }
}

// ---------------- fused RGCN layer (R5 shape — the measured best: 142 µs) ---------
// One 16-node M-tile per BLOCK, 4 waves, each owning 4 relations + 1 kb-quarter
// of the root term; gather-mean straight into A-fragment registers; MFMA vs
// frag-linear Wf; 16KB two-round LDS reduce; fused bias(+ReLU)+store.
// Rotated bucket-index prefetch keeps the next edge's index load off the
// per-edge serial chain. VGPR 56 — R6/R1 showed deeper prefetch (+16 regs)
// regresses via residency; R7/R8 showed wave re-partitioning is neutral;
// R10 showed coalesced streaming loses to this divergent form. Do not perturb.
template <int L>  // L=1: bf16 out + ReLU; L=2: f32 out
__global__ __launch_bounds__(256) void k_layer(const int* __restrict__ off,
                                               const int* __restrict__ bucket,
                                               const u16* __restrict__ x,    // [N,128] bf16
                                               const u16* __restrict__ Wf,   // 64 kb frag-linear
                                               const u16* __restrict__ Rf,   // 4 kb frag-linear
                                               const float* __restrict__ bias,
                                               u16* __restrict__ outb,
                                               float* __restrict__ outf) {
  __shared__ f32x4 red[4][4][64];      // 16 KB
  int w = threadIdx.x >> 6;            // wave 0..3
  int lane = threadIdx.x & 63;
  int node0 = blockIdx.x << 4;         // 50000 = 3125*16, exact grid
  int m = lane & 15;
  int q = lane >> 4;
  int node = node0 + m;                // A-row this lane serves

  f32x4 acc[8];
#pragma unroll
  for (int t = 0; t < 8; ++t)
#pragma unroll
    for (int i = 0; i < 4; ++i) acc[t][i] = 0.0f;

  // ---- root term: this wave does kb = w ----
  {
    bf16x8 a = *(const bf16x8*)(x + ((size_t)node << 7) + w * 32 + (q << 3));
    const u16* bp = Rf + ((size_t)w << 12) + ((size_t)lane << 3);
#pragma unroll
    for (int t = 0; t < 8; ++t) {
      bf16x8 b = *(const bf16x8*)(bp + t * 512);
      acc[t] = __builtin_amdgcn_mfma_f32_16x16x32_bf16(a, b, acc[t], 0, 0, 0);
    }
  }

  // ---- 4 relations per wave: gather-mean into A-frag regs, MFMA vs W_r ----
  for (int rr = 0; rr < 4; ++rr) {
    int r = (w << 2) + rr;
    int seg = (node << 4) + r;
    int o0 = off[seg];
    int o1 = off[seg + 1];

    float a0[8], a1[8], a2[8], a3[8];
#pragma unroll
    for (int j = 0; j < 8; ++j) { a0[j] = 0.f; a1[j] = 0.f; a2[j] = 0.f; a3[j] = 0.f; }

    // rotated prefetch: bucket[i+1] in flight while edge i's rows load/accumulate
    int i = o0;
    int s = (i < o1) ? bucket[i] : 0;
    while (i < o1) {                   // divergent across m; exec-masked
      const u16* xs = x + ((size_t)s << 7) + (q << 3);
      bf16x8 v0 = *(const bf16x8*)(xs);
      bf16x8 v1 = *(const bf16x8*)(xs + 32);
      bf16x8 v2 = *(const bf16x8*)(xs + 64);
      bf16x8 v3 = *(const bf16x8*)(xs + 96);
      int snext = (i + 1 < o1) ? bucket[i + 1] : 0;
#pragma unroll
      for (int j = 0; j < 8; ++j) {
        a0[j] += bf16_to_f32((u16)v0[j]);
        a1[j] += bf16_to_f32((u16)v1[j]);
        a2[j] += bf16_to_f32((u16)v2[j]);
        a3[j] += bf16_to_f32((u16)v3[j]);
      }
      s = snext;
      ++i;
    }

    float sc = (o1 > o0) ? 1.0f / (float)(o1 - o0) : 0.0f;
    bf16x8 f0, f1, f2, f3;
#pragma unroll
    for (int j = 0; j < 8; ++j) {
      f0[j] = (short)f32_to_bf16(a0[j] * sc);
      f1[j] = (short)f32_to_bf16(a1[j] * sc);
      f2[j] = (short)f32_to_bf16(a2[j] * sc);
      f3[j] = (short)f32_to_bf16(a3[j] * sc);
    }

    const u16* bp = Wf + ((size_t)(r * 4) << 12) + ((size_t)lane << 3);
#pragma unroll
    for (int t = 0; t < 8; ++t) {
      bf16x8 b0 = *(const bf16x8*)(bp + t * 512);
      bf16x8 b1 = *(const bf16x8*)(bp + 4096 + t * 512);
      bf16x8 b2 = *(const bf16x8*)(bp + 8192 + t * 512);
      bf16x8 b3 = *(const bf16x8*)(bp + 12288 + t * 512);
      acc[t] = __builtin_amdgcn_mfma_f32_16x16x32_bf16(f0, b0, acc[t], 0, 0, 0);
      acc[t] = __builtin_amdgcn_mfma_f32_16x16x32_bf16(f1, b1, acc[t], 0, 0, 0);
      acc[t] = __builtin_amdgcn_mfma_f32_16x16x32_bf16(f2, b2, acc[t], 0, 0, 0);
      acc[t] = __builtin_amdgcn_mfma_f32_16x16x32_bf16(f3, b3, acc[t], 0, 0, 0);
    }
  }

  // ---- two-round epilogue over 16KB red buffer ----
  // round h: waves write acc[4h..4h+3]; wave w reduces chunk t = 4h + w.
#pragma unroll
  for (int half = 0; half < 2; ++half) {
#pragma unroll
    for (int t = 0; t < 4; ++t) red[w][t][lane] = acc[half * 4 + t];
    __syncthreads();
    {
      f32x4 s0 = red[0][w][lane];
      f32x4 s1 = red[1][w][lane];
      f32x4 s2 = red[2][w][lane];
      f32x4 s3 = red[3][w][lane];
      int tt = half * 4 + w;
      int h = tt * 16 + m;             // C layout col=m, row=q*4+reg [m89]
      float bv = bias[h];
#pragma unroll
      for (int r4 = 0; r4 < 4; ++r4) {
        int n = node0 + (q << 2) + r4;
        float v = s0[r4] + s1[r4] + s2[r4] + s3[r4] + bv;
        if (L == 1) {
          v = v > 0.0f ? v : 0.0f;
          outb[(size_t)n * D + h] = f32_to_bf16(v);
        } else {
          outf[(size_t)n * D + h] = v;
        }
      }
    }
    if (half == 0) __syncthreads();    // WAR: round-A reads done before round-B writes
  }
}

extern "C" void kernel_launch(void* const* d_in, const int* in_sizes, int n_in,
                              void* d_out, int out_size, void* d_ws, size_t ws_size,
                              hipStream_t stream) {
  const int* edge_index = (const int*)d_in[0];
  const int* edge_type  = (const int*)d_in[1];
  const float* emb   = (const float*)d_in[2];
  const float* W1    = (const float*)d_in[3];
  const float* root1 = (const float*)d_in[4];
  const float* b1    = (const float*)d_in[5];
  const float* W2    = (const float*)d_in[6];
  const float* root2 = (const float*)d_in[7];
  const float* b2    = (const float*)d_in[8];
  float* out = (float*)d_out;

  int E = in_sizes[0] / 2;
  const int* src = edge_index;      // row 0
  const int* dst = edge_index + E;  // row 1
  int scanBlocks = (N_SEG4 + 255) / 256;  // 782 (1024-int tiles)

  char* ws = (char*)d_ws;
  size_t off_b = 0;
  auto take = [&](size_t bytes) -> char* {
    char* p = ws + off_b;
    off_b += (bytes + 255) & ~(size_t)255;
    return p;
  };
  int*   cnt    = (int*)take((size_t)N_SEG * 4);
  int*   offs   = (int*)take((size_t)(N_SEG + 1) * 4);
  int*   bsum   = (int*)take((size_t)scanBlocks * 4);
  int*   bucket = (int*)take((size_t)E * 4);
  u16*   embb   = (u16*)take((size_t)N_NODES * D * 2);
  u16*   x1     = (u16*)take((size_t)N_NODES * D * 2);
  u16*   Wf1    = (u16*)take((size_t)64 * 8 * 512 * 2);
  u16*   Rf1    = (u16*)take((size_t)4 * 8 * 512 * 2);
  u16*   Wf2    = (u16*)take((size_t)64 * 8 * 512 * 2);
  u16*   Rf2    = (u16*)take((size_t)4 * 8 * 512 * 2);
  // total ~41 MB — fits comfortably

  int eBlocks4 = ((E + 3) / 4 + 255) / 256;  // 4 edges/thread
  int layerBlocks = N_NODES / 16;            // 3125 blocks, 1 tile per block

  // --- fused prep (zeroes cnt + converts emb + builds all weight frags) ---
  k_prep<<<(PREP_TOTAL + 255) / 256, 256, 0, stream>>>(cnt, emb, embb, W1, Wf1,
                                                       W2, Wf2, root1, Rf1,
                                                       root2, Rf2);

  // --- CSR build (shared by both layers) ---
  k_count<<<eBlocks4, 256, 0, stream>>>(dst, edge_type, cnt, E);
  k_bsum2<<<scanBlocks, 256, 0, stream>>>((const int4*)cnt, bsum, N_SEG4);
  k_bscan2<<<1, 1024, 0, stream>>>(bsum, scanBlocks);
  k_off2<<<scanBlocks, 256, 0, stream>>>((const int4*)cnt, bsum, offs, N_SEG4);
  k_fill<<<eBlocks4, 256, 0, stream>>>(src, dst, edge_type, offs, cnt, bucket, E);

  // --- two fused layers ---
  k_layer<1><<<layerBlocks, 256, 0, stream>>>(offs, bucket, embb, Wf1, Rf1, b1,
                                              x1, nullptr);
  k_layer<2><<<layerBlocks, 256, 0, stream>>>(offs, bucket, x1, Wf2, Rf2, b2,
                                              nullptr, out);
}

// Round 12
// 511.927 us; speedup vs baseline: 1.0803x; 1.0003x over previous
//
#include <hip/hip_runtime.h>

#define N_NODES 50000
#define N_REL 16
#define D 128
#define N_SEG (N_NODES * N_REL)  // 800000
#define N_SEG4 (N_SEG / 4)       // 200000 int4 tiles of cnt

typedef short bf16x8 __attribute__((ext_vector_type(8)));
typedef float f32x4 __attribute__((ext_vector_type(4)));
typedef unsigned short u16;
typedef unsigned int u32;

__device__ __forceinline__ u16 f32_to_bf16(float f) {
  u32 u = __builtin_bit_cast(u32, f);
  u32 r = (u + 0x7FFFu + ((u >> 16) & 1u)) >> 16;
  return (u16)r;
}
__device__ __forceinline__ float bf16_to_f32(u16 h) {
  u32 u = ((u32)h) << 16;
  return __builtin_bit_cast(float, u);
}

// ---------------- zero cnt (uint4 grid-stride; must precede k_prep2's count) ------
__global__ __launch_bounds__(256) void k_zero4(uint4* __restrict__ p, int n4) {
  int i = blockIdx.x * blockDim.x + threadIdx.x;
  int stride = gridDim.x * blockDim.x;
  uint4 z; z.x = z.y = z.z = z.w = 0u;
  for (; i < n4; i += stride) p[i] = z;
}

// ---------------- scan stage 1: 1024-int tiles (int4), per-block sums ----------
__global__ __launch_bounds__(256) void k_bsum2(const int4* __restrict__ cnt4,
                                               int* __restrict__ bsum, int n4) {
  __shared__ int sm[256];
  int idx = blockIdx.x * 256 + threadIdx.x;
  int v = 0;
  if (idx < n4) { int4 c = cnt4[idx]; v = c.x + c.y + c.z + c.w; }
  sm[threadIdx.x] = v;
  __syncthreads();
  for (int s = 128; s > 0; s >>= 1) {
    if (threadIdx.x < s) sm[threadIdx.x] += sm[threadIdx.x + s];
    __syncthreads();
  }
  if (threadIdx.x == 0) bsum[blockIdx.x] = sm[0];
}

// ---------------- scan stage 2: single-iteration exclusive scan (nb <= 1024) ----
__global__ __launch_bounds__(1024) void k_bscan2(int* __restrict__ bsum, int nb) {
  __shared__ int sm[1024];
  int i = threadIdx.x;
  int v = (i < nb) ? bsum[i] : 0;
  sm[i] = v;
  __syncthreads();
  for (int s = 1; s < 1024; s <<= 1) {
    int t = (i >= s) ? sm[i - s] : 0;
    __syncthreads();
    sm[i] += t;
    __syncthreads();
  }
  if (i < nb) bsum[i] = sm[i] - v;   // exclusive
}

// ---------------- scan stage 3: int4 per-element exclusive offsets ----------------
__global__ __launch_bounds__(256) void k_off2(const int4* __restrict__ cnt4,
                                              const int* __restrict__ bsum,
                                              int* __restrict__ off, int n4) {
  __shared__ int sm[256];
  int idx = blockIdx.x * 256 + threadIdx.x;
  int4 c = {0, 0, 0, 0};
  if (idx < n4) c = cnt4[idx];
  int tsum = c.x + c.y + c.z + c.w;
  sm[threadIdx.x] = tsum;
  __syncthreads();
  for (int s = 1; s < 256; s <<= 1) {
    int t = (threadIdx.x >= s) ? sm[threadIdx.x - s] : 0;
    __syncthreads();
    sm[threadIdx.x] += t;
    __syncthreads();
  }
  int base = bsum[blockIdx.x] + sm[threadIdx.x] - tsum;
  if (idx < n4) {
    int4 o;
    o.x = base;
    o.y = base + c.x;
    o.z = o.y + c.y;
    o.w = o.z + c.z;
    ((int4*)off)[idx] = o;
    if (idx == n4 - 1) off[4 * n4] = o.w + c.w;  // off[N_SEG] = E
  }
}

// ---------------- CSR fill (countdown; 4 edges/thread, int4 loads) ----------------
__global__ __launch_bounds__(256) void k_fill(const int* __restrict__ src,
                                              const int* __restrict__ dst,
                                              const int* __restrict__ rel,
                                              const int* __restrict__ off,
                                              int* __restrict__ cnt,
                                              int* __restrict__ bucket, int E) {
  int e = (blockIdx.x * blockDim.x + threadIdx.x) * 4;
  if (e + 3 < E) {
    int4 sv = *(const int4*)(src + e);
    int4 d  = *(const int4*)(dst + e);
    int4 r  = *(const int4*)(rel + e);
    int seg, old;
    seg = d.x * N_REL + r.x; old = atomicSub(&cnt[seg], 1);
    bucket[off[seg] + old - 1] = sv.x;
    seg = d.y * N_REL + r.y; old = atomicSub(&cnt[seg], 1);
    bucket[off[seg] + old - 1] = sv.y;
    seg = d.z * N_REL + r.z; old = atomicSub(&cnt[seg], 1);
    bucket[off[seg] + old - 1] = sv.z;
    seg = d.w * N_REL + r.w; old = atomicSub(&cnt[seg], 1);
    bucket[off[seg] + old - 1] = sv.w;
  } else {
    for (; e < E; ++e) {
      int seg = dst[e] * N_REL + rel[e];
      int old = atomicSub(&cnt[seg], 1);          // old in [1, cnt]
      bucket[off[seg] + old - 1] = src[e];
    }
  }
}

// -------- fused prep2: edge-count (atomic-bound) OVERLAPPED with convert/wfrag ----
// R12: k_count's 1.6M L2 atomics are latency-bound; the convert + weight-frag
// regions are BW-bound. Running them as tid-regions of ONE kernel lets the
// machine do both at once instead of serially (critical path loses
// ~min(T_count, T_prep)). Count region first so its blocks launch earliest.
__device__ __forceinline__ void wfrag_one(const float* __restrict__ W,
                                          u16* __restrict__ Wf, int tid) {
  int lane = tid & 63;
  int t = (tid >> 6) & 7;
  int kb = tid >> 9;
  int h = t * 16 + (lane & 15);
  int kbase = kb * 32 + ((lane >> 4) << 3);
  bf16x8 frag;
#pragma unroll
  for (int j = 0; j < 8; ++j) {
    int k = kbase + j;
    frag[j] = (short)f32_to_bf16(W[(size_t)(k >> 7) * (D * D) + (size_t)(k & 127) * D + h]);
  }
  *(bf16x8*)(Wf + (size_t)tid * 8) = frag;
}

#define CVT_N4 (N_NODES * D / 4)         // 1,600,000
#define WF_T (64 * 8 * 64)               // 32768
#define RF_T (4 * 8 * 64)                // 2048

__global__ __launch_bounds__(256) void k_prep2(const int* __restrict__ dst,
                                               const int* __restrict__ rel,
                                               int* __restrict__ cnt,
                                               int countT, int E,
                                               const float* __restrict__ emb,
                                               u16* __restrict__ embb,
                                               const float* __restrict__ W1,
                                               u16* __restrict__ Wf1,
                                               const float* __restrict__ W2,
                                               u16* __restrict__ Wf2,
                                               const float* __restrict__ R1,
                                               u16* __restrict__ Rf1,
                                               const float* __restrict__ R2,
                                               u16* __restrict__ Rf2) {
  int tid = blockIdx.x * blockDim.x + threadIdx.x;
  if (tid < countT) {                // edge-count region (4 edges/thread)
    int e = tid * 4;
    if (e + 3 < E) {
      int4 d = *(const int4*)(dst + e);
      int4 r = *(const int4*)(rel + e);
      atomicAdd(&cnt[d.x * N_REL + r.x], 1);
      atomicAdd(&cnt[d.y * N_REL + r.y], 1);
      atomicAdd(&cnt[d.z * N_REL + r.z], 1);
      atomicAdd(&cnt[d.w * N_REL + r.w], 1);
    } else {
      for (; e < E; ++e) atomicAdd(&cnt[dst[e] * N_REL + rel[e]], 1);
    }
    return;
  }
  int u = tid - countT;
  if (u < CVT_N4) {                  // f32 -> bf16 embedding convert
    float4 v = ((const float4*)emb)[u];
    u32 p0 = (u32)f32_to_bf16(v.x) | ((u32)f32_to_bf16(v.y) << 16);
    u32 p1 = (u32)f32_to_bf16(v.z) | ((u32)f32_to_bf16(v.w) << 16);
    ((u32*)embb)[u * 2] = p0;
    ((u32*)embb)[u * 2 + 1] = p1;
    return;
  }
  u -= CVT_N4;
  if (u < WF_T) { wfrag_one(W1, Wf1, u); return; }
  u -= WF_T;
  if (u < WF_T) { wfrag_one(W2, Wf2, u); return; }
  u -= WF_T;
  if (u < RF_T) { wfrag_one(R1, Rf1, u); return; }
  u -= RF_T;
  if (u < RF_T) { wfrag_one(R2, Rf2, u); return; }
}

// ---------------- fused RGCN layer (R5 shape — the measured best: 142 µs) ---------
// One 16-node M-tile per BLOCK, 4 waves, each owning 4 relations + 1 kb-quarter
// of the root term; gather-mean straight into A-fragment registers; MFMA vs
// frag-linear Wf; 16KB two-round LDS reduce; fused bias(+ReLU)+store.
// Rotated bucket-index prefetch keeps the next edge's index load off the
// per-edge serial chain. VGPR 56 — R6/R1 showed deeper prefetch (+16 regs)
// regresses via residency; R7/R8 showed wave re-partitioning is neutral;
// R10 showed coalesced streaming loses to this divergent form. Do not perturb.
template <int L>  // L=1: bf16 out + ReLU; L=2: f32 out
__global__ __launch_bounds__(256) void k_layer(const int* __restrict__ off,
                                               const int* __restrict__ bucket,
                                               const u16* __restrict__ x,    // [N,128] bf16
                                               const u16* __restrict__ Wf,   // 64 kb frag-linear
                                               const u16* __restrict__ Rf,   // 4 kb frag-linear
                                               const float* __restrict__ bias,
                                               u16* __restrict__ outb,
                                               float* __restrict__ outf) {
  __shared__ f32x4 red[4][4][64];      // 16 KB
  int w = threadIdx.x >> 6;            // wave 0..3
  int lane = threadIdx.x & 63;
  int node0 = blockIdx.x << 4;         // 50000 = 3125*16, exact grid
  int m = lane & 15;
  int q = lane >> 4;
  int node = node0 + m;                // A-row this lane serves

  f32x4 acc[8];
#pragma unroll
  for (int t = 0; t < 8; ++t)
#pragma unroll
    for (int i = 0; i < 4; ++i) acc[t][i] = 0.0f;

  // ---- root term: this wave does kb = w ----
  {
    bf16x8 a = *(const bf16x8*)(x + ((size_t)node << 7) + w * 32 + (q << 3));
    const u16* bp = Rf + ((size_t)w << 12) + ((size_t)lane << 3);
#pragma unroll
    for (int t = 0; t < 8; ++t) {
      bf16x8 b = *(const bf16x8*)(bp + t * 512);
      acc[t] = __builtin_amdgcn_mfma_f32_16x16x32_bf16(a, b, acc[t], 0, 0, 0);
    }
  }

  // ---- 4 relations per wave: gather-mean into A-frag regs, MFMA vs W_r ----
  for (int rr = 0; rr < 4; ++rr) {
    int r = (w << 2) + rr;
    int seg = (node << 4) + r;
    int o0 = off[seg];
    int o1 = off[seg + 1];

    float a0[8], a1[8], a2[8], a3[8];
#pragma unroll
    for (int j = 0; j < 8; ++j) { a0[j] = 0.f; a1[j] = 0.f; a2[j] = 0.f; a3[j] = 0.f; }

    // rotated prefetch: bucket[i+1] in flight while edge i's rows load/accumulate
    int i = o0;
    int s = (i < o1) ? bucket[i] : 0;
    while (i < o1) {                   // divergent across m; exec-masked
      const u16* xs = x + ((size_t)s << 7) + (q << 3);
      bf16x8 v0 = *(const bf16x8*)(xs);
      bf16x8 v1 = *(const bf16x8*)(xs + 32);
      bf16x8 v2 = *(const bf16x8*)(xs + 64);
      bf16x8 v3 = *(const bf16x8*)(xs + 96);
      int snext = (i + 1 < o1) ? bucket[i + 1] : 0;
#pragma unroll
      for (int j = 0; j < 8; ++j) {
        a0[j] += bf16_to_f32((u16)v0[j]);
        a1[j] += bf16_to_f32((u16)v1[j]);
        a2[j] += bf16_to_f32((u16)v2[j]);
        a3[j] += bf16_to_f32((u16)v3[j]);
      }
      s = snext;
      ++i;
    }

    float sc = (o1 > o0) ? 1.0f / (float)(o1 - o0) : 0.0f;
    bf16x8 f0, f1, f2, f3;
#pragma unroll
    for (int j = 0; j < 8; ++j) {
      f0[j] = (short)f32_to_bf16(a0[j] * sc);
      f1[j] = (short)f32_to_bf16(a1[j] * sc);
      f2[j] = (short)f32_to_bf16(a2[j] * sc);
      f3[j] = (short)f32_to_bf16(a3[j] * sc);
    }

    const u16* bp = Wf + ((size_t)(r * 4) << 12) + ((size_t)lane << 3);
#pragma unroll
    for (int t = 0; t < 8; ++t) {
      bf16x8 b0 = *(const bf16x8*)(bp + t * 512);
      bf16x8 b1 = *(const bf16x8*)(bp + 4096 + t * 512);
      bf16x8 b2 = *(const bf16x8*)(bp + 8192 + t * 512);
      bf16x8 b3 = *(const bf16x8*)(bp + 12288 + t * 512);
      acc[t] = __builtin_amdgcn_mfma_f32_16x16x32_bf16(f0, b0, acc[t], 0, 0, 0);
      acc[t] = __builtin_amdgcn_mfma_f32_16x16x32_bf16(f1, b1, acc[t], 0, 0, 0);
      acc[t] = __builtin_amdgcn_mfma_f32_16x16x32_bf16(f2, b2, acc[t], 0, 0, 0);
      acc[t] = __builtin_amdgcn_mfma_f32_16x16x32_bf16(f3, b3, acc[t], 0, 0, 0);
    }
  }

  // ---- two-round epilogue over 16KB red buffer ----
  // round h: waves write acc[4h..4h+3]; wave w reduces chunk t = 4h + w.
#pragma unroll
  for (int half = 0; half < 2; ++half) {
#pragma unroll
    for (int t = 0; t < 4; ++t) red[w][t][lane] = acc[half * 4 + t];
    __syncthreads();
    {
      f32x4 s0 = red[0][w][lane];
      f32x4 s1 = red[1][w][lane];
      f32x4 s2 = red[2][w][lane];
      f32x4 s3 = red[3][w][lane];
      int tt = half * 4 + w;
      int h = tt * 16 + m;             // C layout col=m, row=q*4+reg [m89]
      float bv = bias[h];
#pragma unroll
      for (int r4 = 0; r4 < 4; ++r4) {
        int n = node0 + (q << 2) + r4;
        float v = s0[r4] + s1[r4] + s2[r4] + s3[r4] + bv;
        if (L == 1) {
          v = v > 0.0f ? v : 0.0f;
          outb[(size_t)n * D + h] = f32_to_bf16(v);
        } else {
          outf[(size_t)n * D + h] = v;
        }
      }
    }
    if (half == 0) __syncthreads();    // WAR: round-A reads done before round-B writes
  }
}

extern "C" void kernel_launch(void* const* d_in, const int* in_sizes, int n_in,
                              void* d_out, int out_size, void* d_ws, size_t ws_size,
                              hipStream_t stream) {
  const int* edge_index = (const int*)d_in[0];
  const int* edge_type  = (const int*)d_in[1];
  const float* emb   = (const float*)d_in[2];
  const float* W1    = (const float*)d_in[3];
  const float* root1 = (const float*)d_in[4];
  const float* b1    = (const float*)d_in[5];
  const float* W2    = (const float*)d_in[6];
  const float* root2 = (const float*)d_in[7];
  const float* b2    = (const float*)d_in[8];
  float* out = (float*)d_out;

  int E = in_sizes[0] / 2;
  const int* src = edge_index;      // row 0
  const int* dst = edge_index + E;  // row 1
  int scanBlocks = (N_SEG4 + 255) / 256;  // 782 (1024-int tiles)

  char* ws = (char*)d_ws;
  size_t off_b = 0;
  auto take = [&](size_t bytes) -> char* {
    char* p = ws + off_b;
    off_b += (bytes + 255) & ~(size_t)255;
    return p;
  };
  int*   cnt    = (int*)take((size_t)N_SEG * 4);
  int*   offs   = (int*)take((size_t)(N_SEG + 1) * 4);
  int*   bsum   = (int*)take((size_t)scanBlocks * 4);
  int*   bucket = (int*)take((size_t)E * 4);
  u16*   embb   = (u16*)take((size_t)N_NODES * D * 2);
  u16*   x1     = (u16*)take((size_t)N_NODES * D * 2);
  u16*   Wf1    = (u16*)take((size_t)64 * 8 * 512 * 2);
  u16*   Rf1    = (u16*)take((size_t)4 * 8 * 512 * 2);
  u16*   Wf2    = (u16*)take((size_t)64 * 8 * 512 * 2);
  u16*   Rf2    = (u16*)take((size_t)4 * 8 * 512 * 2);
  // total ~41 MB — fits comfortably

  int countT = (E + 3) / 4;                  // 4 edges/thread count region
  int prepTotal = countT + CVT_N4 + 2 * WF_T + 2 * RF_T;
  int eBlocks4 = (countT + 255) / 256;       // 4 edges/thread (k_fill)
  int layerBlocks = N_NODES / 16;            // 3125 blocks, 1 tile per block

  // --- CSR count overlapped with prep (cnt zeroed first — tiny kernel) ---
  k_zero4<<<512, 256, 0, stream>>>((uint4*)cnt, N_SEG4);
  k_prep2<<<(prepTotal + 255) / 256, 256, 0, stream>>>(dst, edge_type, cnt,
                                                       countT, E, emb, embb,
                                                       W1, Wf1, W2, Wf2,
                                                       root1, Rf1, root2, Rf2);

  // --- scan + fill ---
  k_bsum2<<<scanBlocks, 256, 0, stream>>>((const int4*)cnt, bsum, N_SEG4);
  k_bscan2<<<1, 1024, 0, stream>>>(bsum, scanBlocks);
  k_off2<<<scanBlocks, 256, 0, stream>>>((const int4*)cnt, bsum, offs, N_SEG4);
  k_fill<<<eBlocks4, 256, 0, stream>>>(src, dst, edge_type, offs, cnt, bucket, E);

  // --- two fused layers ---
  k_layer<1><<<layerBlocks, 256, 0, stream>>>(offs, bucket, embb, Wf1, Rf1, b1,
                                              x1, nullptr);
  k_layer<2><<<layerBlocks, 256, 0, stream>>>(offs, bucket, x1, Wf2, Rf2, b2,
                                              nullptr, out);
}